// Round 7
// baseline (89.453 us; speedup 1.0000x reference)
//
#include <hip/hip_runtime.h>

constexpr int N_NODES = 50000;
constexpr int KNB = 12;       // neighbors per node
constexpr int F = 128;        // F_IN == F_OUT
constexpr float ALPHA = 0.2f; // LeakyReLU slope
constexpr int BM = 64;        // nodes per GEMM tile
constexpr int TILES_PER_BLK = 2;

typedef __bf16 bf16x8 __attribute__((ext_vector_type(8)));
typedef float  f32x4  __attribute__((ext_vector_type(4)));

__device__ __forceinline__ unsigned bfr(float f) {
    unsigned u = __float_as_uint(f);
    return (u + 0x7fffu + ((u >> 16) & 1u)) >> 16;
}
__device__ __forceinline__ unsigned pack2(float lo, float hi) {
    return bfr(lo) | (bfr(hi) << 16);
}
__device__ __forceinline__ float bf2f(unsigned bits16) {
    return __uint_as_float(bits16 << 16);
}

// ---------------- Kernel 0: W transpose + bf16, PRE-SWIZZLED ----------------
__global__ __launch_bounds__(256) void gat_prep(const float* __restrict__ Wself,
                                                const float* __restrict__ Wnb,
                                                unsigned* __restrict__ Wt) {
    const int gid = blockIdx.x * 256 + threadIdx.x;  // 16384 total
    const int n  = gid >> 6;
    const int kp = gid & 63;        // k-pair 0..63
    const int k16 = kp >> 2;
    const int sub = kp & 3;
    const float* src = (n < F) ? (Wself + n) : (Wnb + (n - F));
    const float f0 = src[(size_t)(kp * 2)     * F];
    const float f1 = src[(size_t)(kp * 2 + 1) * F];
    Wt[n * 64 + (k16 ^ (n & 7)) * 4 + sub] = pack2(f0, f1);
}

// ---------------- Kernel 1: fused dual GEMM via MFMA ----------------
__global__ __launch_bounds__(256, 2) void gat_gemm(
    const float* __restrict__ x,
    const unsigned* __restrict__ Wt,   // [256][16] uint4, pre-swizzled
    const float* __restrict__ a,
    const float* __restrict__ bias,
    unsigned short* __restrict__ selfb,
    unsigned short* __restrict__ hb,
    float* __restrict__ s_in,
    float* __restrict__ s_out)
{
    __shared__ uint4 ldsX[BM * 16];    // 16KB
    __shared__ uint4 ldsW[256 * 16];   // 64KB

    const int t = threadIdx.x;
    const int w    = t >> 6;
    const int lane = t & 63;
    const int lq   = lane >> 4;
    const int lr   = lane & 15;

    // ---- stage W via async DMA, once per block ----
    const uint4* Wt4 = reinterpret_cast<const uint4*>(Wt);
#pragma unroll
    for (int i = 0; i < 16; ++i) {
        const int ch = w * 16 + i;
        const uint4* gp = Wt4 + ch * 64 + lane;
        uint4* lp = ldsW + ch * 64;
        __builtin_amdgcn_global_load_lds(
            (const __attribute__((address_space(1))) void*)gp,
            (__attribute__((address_space(3))) void*)lp, 16, 0, 0);
    }

    const bf16x8* fx = reinterpret_cast<const bf16x8*>(ldsX);
    const bf16x8* fw = reinterpret_cast<const bf16x8*>(ldsW);
    float* sbuf = reinterpret_cast<float*>(ldsX);

    for (int it = 0; it < TILES_PER_BLK; ++it) {
        const int base = (blockIdx.x * TILES_PER_BLK + it) * BM;

        // ---- stage X tile (fp32 -> bf16 pack) ----
#pragma unroll
        for (int i = 0; i < 4; ++i) {
            const int idx = t + i * 256;       // row*16 + k16
            const int row = idx >> 4;
            const int k16 = idx & 15;
            int gr = base + row; if (gr >= N_NODES) gr = N_NODES - 1;
            const float4* xp = reinterpret_cast<const float4*>(x + (size_t)gr * F + k16 * 8);
            const float4 f0 = xp[0];
            const float4 f1 = xp[1];
            uint4 v;
            v.x = pack2(f0.x, f0.y); v.y = pack2(f0.z, f0.w);
            v.z = pack2(f1.x, f1.y); v.w = pack2(f1.z, f1.w);
            ldsX[row * 16 + (k16 ^ (row & 7))] = v;
        }
        __syncthreads();   // X visible; first iter also drains W DMA

        f32x4 acc[4][4];   // [col-tile mt][row-tile rt]
#pragma unroll
        for (int mt = 0; mt < 4; ++mt)
#pragma unroll
            for (int rt = 0; rt < 4; ++rt)
                acc[mt][rt] = f32x4{0.f, 0.f, 0.f, 0.f};

#pragma unroll
        for (int s = 0; s < 4; ++s) {
            bf16x8 wf[4], xf[4];
#pragma unroll
            for (int mt = 0; mt < 4; ++mt) {
                const int n = w * 64 + mt * 16 + lr;
                wf[mt] = fw[n * 16 + ((s * 4 + lq) ^ (n & 7))];
            }
#pragma unroll
            for (int rt = 0; rt < 4; ++rt) {
                const int r = rt * 16 + lr;
                xf[rt] = fx[r * 16 + ((s * 4 + lq) ^ (r & 7))];
            }
#pragma unroll
            for (int mt = 0; mt < 4; ++mt)
#pragma unroll
                for (int rt = 0; rt < 4; ++rt)
                    acc[mt][rt] = __builtin_amdgcn_mfma_f32_16x16x32_bf16(wf[mt], xf[rt], acc[mt][rt], 0, 0, 0);
        }

        __syncthreads();   // frag reads done; ldsX reusable as sbuf

        // D mapping: acc[mt][rt][r] -> col = w*64+mt*16+lq*4+r, row = base+rt*16+lr.
        if (w < 2) {
#pragma unroll
            for (int mt = 0; mt < 4; ++mt) {
                const int col0 = w * 64 + mt * 16 + lq * 4;
                const float4 b4 = *reinterpret_cast<const float4*>(bias + col0);
#pragma unroll
                for (int rt = 0; rt < 4; ++rt) {
                    const int row = base + rt * 16 + lr;
                    if (row < N_NODES) {
                        const f32x4 v = acc[mt][rt];
                        uint2 pk{pack2(v[0] + b4.x, v[1] + b4.y), pack2(v[2] + b4.z, v[3] + b4.w)};
                        *reinterpret_cast<uint2*>(selfb + (size_t)row * F + col0) = pk;
                    }
                }
            }
        } else {
            float spin[4] = {0.f, 0.f, 0.f, 0.f};
            float spout[4] = {0.f, 0.f, 0.f, 0.f};
#pragma unroll
            for (int mt = 0; mt < 4; ++mt) {
                const int colh0 = (w - 2) * 64 + mt * 16 + lq * 4;
                const float4 al = *reinterpret_cast<const float4*>(a + colh0);
                const float4 ah = *reinterpret_cast<const float4*>(a + F + colh0);
#pragma unroll
                for (int rt = 0; rt < 4; ++rt) {
                    const int row = base + rt * 16 + lr;
                    const f32x4 v = acc[mt][rt];
                    if (row < N_NODES) {
                        uint2 pk{pack2(v[0], v[1]), pack2(v[2], v[3])};
                        *reinterpret_cast<uint2*>(hb + (size_t)row * F + colh0) = pk;
                    }
                    spin[rt]  = fmaf(v[0], al.x, fmaf(v[1], al.y, fmaf(v[2], al.z, fmaf(v[3], al.w, spin[rt]))));
                    spout[rt] = fmaf(v[0], ah.x, fmaf(v[1], ah.y, fmaf(v[2], ah.z, fmaf(v[3], ah.w, spout[rt]))));
                }
            }
#pragma unroll
            for (int rt = 0; rt < 4; ++rt) {
                spin[rt]  += __shfl_xor(spin[rt], 16);
                spin[rt]  += __shfl_xor(spin[rt], 32);
                spout[rt] += __shfl_xor(spout[rt], 16);
                spout[rt] += __shfl_xor(spout[rt], 32);
            }
            if (lq == 0) {
#pragma unroll
                for (int rt = 0; rt < 4; ++rt) {
                    sbuf[(w - 2) * 128 + rt * 16 + lr]      = spin[rt];
                    sbuf[(w - 2) * 128 + 64 + rt * 16 + lr] = spout[rt];
                }
            }
        }
        __syncthreads();
        if (t < 128) {
            const int i = t & 63;
            const int row = base + i;
            if (row < N_NODES) {
                if (t < 64) s_in[row]  = sbuf[i] + sbuf[128 + i];
                else        s_out[row] = sbuf[64 + i] + sbuf[192 + i];
            }
        }
        __syncthreads();   // sbuf reads done before next tile overwrites ldsX
    }
}

// ---------------- Kernel 2: attention + aggregation ----------------
__global__ __launch_bounds__(256) void gat_attn(
    const uint4* __restrict__ hbU4,      // h bf16: [N][16] uint4
    const uint4* __restrict__ selfbU4,   // act_self+bias bf16: [N][16] uint4
    const float* __restrict__ s_in,
    const float* __restrict__ s_out,
    const int* __restrict__ colidx,
    const float* __restrict__ adj,
    float* __restrict__ out)
{
    const int wid  = threadIdx.x >> 6;
    const int lane = threadIdx.x & 63;
    const int lr   = lane & 15;
    const int node = (blockIdx.x * 4 + wid) * 4 + (lane >> 4);   // 16 nodes/block

    float e = -1e30f;
    int c = 0;
    float av = 0.f;
    if (lr < KNB) {
        c  = colidx[node * KNB + lr];
        av = adj[node * KNB + lr];
        const float ev = s_in[node] + s_out[c];
        e = ev > 0.f ? ev : ALPHA * ev;
    }
    float m = e;
#pragma unroll
    for (int msk = 8; msk >= 1; msk >>= 1) m = fmaxf(m, __shfl_xor(m, msk));
    const float p = (lr < KNB) ? __expf(e - m) : 0.f;
    float ssum = p;
#pragma unroll
    for (int msk = 8; msk >= 1; msk >>= 1) ssum += __shfl_xor(ssum, msk);
    const float att = p / ssum * av;

    const uint4 sb = selfbU4[(size_t)node * 16 + lr];
    float accf[8];
    accf[0] = bf2f(sb.x & 0xffffu); accf[1] = bf2f(sb.x >> 16);
    accf[2] = bf2f(sb.y & 0xffffu); accf[3] = bf2f(sb.y >> 16);
    accf[4] = bf2f(sb.z & 0xffffu); accf[5] = bf2f(sb.z >> 16);
    accf[6] = bf2f(sb.w & 0xffffu); accf[7] = bf2f(sb.w >> 16);

    const int gbase = lane & 48;
#pragma unroll
    for (int j = 0; j < KNB; ++j) {
        const float aj = __shfl(att, gbase + j);
        const int   cj = __shfl(c,   gbase + j);
        const uint4 u = hbU4[(size_t)cj * 16 + lr];
        accf[0] = fmaf(aj, bf2f(u.x & 0xffffu), accf[0]);
        accf[1] = fmaf(aj, bf2f(u.x >> 16),     accf[1]);
        accf[2] = fmaf(aj, bf2f(u.y & 0xffffu), accf[2]);
        accf[3] = fmaf(aj, bf2f(u.y >> 16),     accf[3]);
        accf[4] = fmaf(aj, bf2f(u.z & 0xffffu), accf[4]);
        accf[5] = fmaf(aj, bf2f(u.z >> 16),     accf[5]);
        accf[6] = fmaf(aj, bf2f(u.w & 0xffffu), accf[6]);
        accf[7] = fmaf(aj, bf2f(u.w >> 16),     accf[7]);
    }
    float4* op = reinterpret_cast<float4*>(out + (size_t)node * F + lr * 8);
    op[0] = float4{accf[0], accf[1], accf[2], accf[3]};
    op[1] = float4{accf[4], accf[5], accf[6], accf[7]};
}

extern "C" void kernel_launch(void* const* d_in, const int* in_sizes, int n_in,
                              void* d_out, int out_size, void* d_ws, size_t ws_size,
                              hipStream_t stream) {
    const float* x     = (const float*)d_in[0];
    const float* adj   = (const float*)d_in[1];
    // d_in[2] = row: implicit (edges sorted, exactly K per node)
    const int*   col   = (const int*)d_in[3];
    const float* Wself = (const float*)d_in[4];
    const float* Wnb   = (const float*)d_in[5];
    const float* a     = (const float*)d_in[6];
    const float* bias  = (const float*)d_in[7];
    float* out = (float*)d_out;

    char* ws = (char*)d_ws;
    unsigned short* hb    = (unsigned short*)ws;         // 12,800,000 B
    unsigned short* selfb = (unsigned short*)(ws + 12800000);  // 12,800,000 B
    float* s_in  = (float*)(ws + 25600000);              // 200,000 B
    float* s_out = (float*)(ws + 25800000);              // 200,000 B
    unsigned* Wt = (unsigned*)(ws + 26000000);           // 65,536 B

    gat_prep<<<64, 256, 0, stream>>>(Wself, Wnb, Wt);
    const int ntiles = (N_NODES + BM - 1) / BM;                       // 782
    const int nblk   = (ntiles + TILES_PER_BLK - 1) / TILES_PER_BLK;  // 391
    // ATTRIBUTION ROUND: gat_gemm is idempotent; launch 3x to measure its cost
    // from the total-duration delta vs R6 (dur' = dur_R6 + 2*(gemm+gap)).
    gat_gemm<<<nblk, 256, 0, stream>>>(x, Wt, a, bias, selfb, hb, s_in, s_out);
    gat_gemm<<<nblk, 256, 0, stream>>>(x, Wt, a, bias, selfb, hb, s_in, s_out);
    gat_gemm<<<nblk, 256, 0, stream>>>(x, Wt, a, bias, selfb, hb, s_in, s_out);
    gat_attn<<<(N_NODES + 15) / 16, 256, 0, stream>>>((const uint4*)hb, (const uint4*)selfb,
                                                      s_in, s_out, col, adj, out);
}

// Round 8
// 52.587 us; speedup vs baseline: 1.7010x; 1.7010x over previous
//
#include <hip/hip_runtime.h>

constexpr int N_NODES = 50000;
constexpr int KNB = 12;       // neighbors per node
constexpr int F = 128;        // F_IN == F_OUT
constexpr float ALPHA = 0.2f; // LeakyReLU slope
constexpr int BM = 64;        // nodes per GEMM tile
constexpr int TILES_PER_BLK = 2;

typedef __bf16 bf16x8 __attribute__((ext_vector_type(8)));
typedef __bf16 bf16x2 __attribute__((ext_vector_type(2)));
typedef float  f32x4  __attribute__((ext_vector_type(4)));

// Native f32->bf16 pack: compiler emits v_cvt_pk_bf16_f32 (hardware RNE).
__device__ __forceinline__ unsigned pack2(float lo, float hi) {
    bf16x2 v;
    v[0] = (__bf16)lo;
    v[1] = (__bf16)hi;
    return __builtin_bit_cast(unsigned, v);
}
__device__ __forceinline__ float bf2f(unsigned bits16) {
    return __uint_as_float(bits16 << 16);
}

// ---------------- Kernel 0: W transpose + bf16, PRE-SWIZZLED ----------------
// frag(n, k16) = 8 bf16 of W[k16*8 .. k16*8+7][n], n in [0,256)
// stored at uint4 index n*16 + (k16 ^ (n&7))  (the LDS layout the GEMM reads).
__global__ __launch_bounds__(256) void gat_prep(const float* __restrict__ Wself,
                                                const float* __restrict__ Wnb,
                                                unsigned* __restrict__ Wt) {
    const int gid = blockIdx.x * 256 + threadIdx.x;  // 16384 total
    const int n  = gid >> 6;
    const int kp = gid & 63;        // k-pair 0..63
    const int k16 = kp >> 2;
    const int sub = kp & 3;
    const float* src = (n < F) ? (Wself + n) : (Wnb + (n - F));
    const float f0 = src[(size_t)(kp * 2)     * F];
    const float f1 = src[(size_t)(kp * 2 + 1) * F];
    Wt[n * 64 + (k16 ^ (n & 7)) * 4 + sub] = pack2(f0, f1);
}

// ---------------- Kernel 1: fused dual GEMM via MFMA ----------------
// Each block: stage W once (DMA), then process TILES_PER_BLK row-tiles of 64 nodes.
//   waves 0,1 (cols 0..127):  selfb = bf16(x@Wself + bias)
//   waves 2,3 (cols 128..255): hb = bf16(x@Wnb); s_in/s_out reduced+stored
__global__ __launch_bounds__(256, 2) void gat_gemm(
    const float* __restrict__ x,
    const unsigned* __restrict__ Wt,   // [256][16] uint4, pre-swizzled
    const float* __restrict__ a,
    const float* __restrict__ bias,
    unsigned short* __restrict__ selfb,
    unsigned short* __restrict__ hb,
    float* __restrict__ s_in,
    float* __restrict__ s_out)
{
    __shared__ uint4 ldsX[BM * 16];    // 16KB
    __shared__ uint4 ldsW[256 * 16];   // 64KB

    const int t = threadIdx.x;
    const int w    = t >> 6;
    const int lane = t & 63;
    const int lq   = lane >> 4;
    const int lr   = lane & 15;

    // ---- stage W via async DMA, once per block ----
    const uint4* Wt4 = reinterpret_cast<const uint4*>(Wt);
#pragma unroll
    for (int i = 0; i < 16; ++i) {
        const int ch = w * 16 + i;
        const uint4* gp = Wt4 + ch * 64 + lane;
        uint4* lp = ldsW + ch * 64;
        __builtin_amdgcn_global_load_lds(
            (const __attribute__((address_space(1))) void*)gp,
            (__attribute__((address_space(3))) void*)lp, 16, 0, 0);
    }

    const bf16x8* fx = reinterpret_cast<const bf16x8*>(ldsX);
    const bf16x8* fw = reinterpret_cast<const bf16x8*>(ldsW);
    float* sbuf = reinterpret_cast<float*>(ldsX);

    for (int it = 0; it < TILES_PER_BLK; ++it) {
        const int base = (blockIdx.x * TILES_PER_BLK + it) * BM;

        // ---- stage X tile (fp32 -> bf16 pack via v_cvt_pk_bf16_f32) ----
#pragma unroll
        for (int i = 0; i < 4; ++i) {
            const int idx = t + i * 256;       // row*16 + k16
            const int row = idx >> 4;
            const int k16 = idx & 15;
            int gr = base + row; if (gr >= N_NODES) gr = N_NODES - 1;
            const float4* xp = reinterpret_cast<const float4*>(x + (size_t)gr * F + k16 * 8);
            const float4 f0 = xp[0];
            const float4 f1 = xp[1];
            uint4 v;
            v.x = pack2(f0.x, f0.y); v.y = pack2(f0.z, f0.w);
            v.z = pack2(f1.x, f1.y); v.w = pack2(f1.z, f1.w);
            ldsX[row * 16 + (k16 ^ (row & 7))] = v;
        }
        __syncthreads();   // X visible; first iter also drains W DMA

        f32x4 acc[4][4];   // [col-tile mt][row-tile rt]
#pragma unroll
        for (int mt = 0; mt < 4; ++mt)
#pragma unroll
            for (int rt = 0; rt < 4; ++rt)
                acc[mt][rt] = f32x4{0.f, 0.f, 0.f, 0.f};

#pragma unroll
        for (int s = 0; s < 4; ++s) {
            bf16x8 wf[4], xf[4];
#pragma unroll
            for (int mt = 0; mt < 4; ++mt) {
                const int n = w * 64 + mt * 16 + lr;
                wf[mt] = fw[n * 16 + ((s * 4 + lq) ^ (n & 7))];
            }
#pragma unroll
            for (int rt = 0; rt < 4; ++rt) {
                const int r = rt * 16 + lr;
                xf[rt] = fx[r * 16 + ((s * 4 + lq) ^ (r & 7))];
            }
#pragma unroll
            for (int mt = 0; mt < 4; ++mt)
#pragma unroll
                for (int rt = 0; rt < 4; ++rt)
                    acc[mt][rt] = __builtin_amdgcn_mfma_f32_16x16x32_bf16(wf[mt], xf[rt], acc[mt][rt], 0, 0, 0);
        }

        __syncthreads();   // frag reads done; ldsX reusable as sbuf

        // D mapping: acc[mt][rt][r] -> col = w*64+mt*16+lq*4+r, row = base+rt*16+lr.
        if (w < 2) {
#pragma unroll
            for (int mt = 0; mt < 4; ++mt) {
                const int col0 = w * 64 + mt * 16 + lq * 4;
                const float4 b4 = *reinterpret_cast<const float4*>(bias + col0);
#pragma unroll
                for (int rt = 0; rt < 4; ++rt) {
                    const int row = base + rt * 16 + lr;
                    if (row < N_NODES) {
                        const f32x4 v = acc[mt][rt];
                        uint2 pk{pack2(v[0] + b4.x, v[1] + b4.y), pack2(v[2] + b4.z, v[3] + b4.w)};
                        *reinterpret_cast<uint2*>(selfb + (size_t)row * F + col0) = pk;
                    }
                }
            }
        } else {
            float spin[4] = {0.f, 0.f, 0.f, 0.f};
            float spout[4] = {0.f, 0.f, 0.f, 0.f};
#pragma unroll
            for (int mt = 0; mt < 4; ++mt) {
                const int colh0 = (w - 2) * 64 + mt * 16 + lq * 4;
                const float4 al = *reinterpret_cast<const float4*>(a + colh0);
                const float4 ah = *reinterpret_cast<const float4*>(a + F + colh0);
#pragma unroll
                for (int rt = 0; rt < 4; ++rt) {
                    const int row = base + rt * 16 + lr;
                    const f32x4 v = acc[mt][rt];
                    if (row < N_NODES) {
                        uint2 pk{pack2(v[0], v[1]), pack2(v[2], v[3])};
                        *reinterpret_cast<uint2*>(hb + (size_t)row * F + colh0) = pk;
                    }
                    spin[rt]  = fmaf(v[0], al.x, fmaf(v[1], al.y, fmaf(v[2], al.z, fmaf(v[3], al.w, spin[rt]))));
                    spout[rt] = fmaf(v[0], ah.x, fmaf(v[1], ah.y, fmaf(v[2], ah.z, fmaf(v[3], ah.w, spout[rt]))));
                }
            }
#pragma unroll
            for (int rt = 0; rt < 4; ++rt) {
                spin[rt]  += __shfl_xor(spin[rt], 16);
                spin[rt]  += __shfl_xor(spin[rt], 32);
                spout[rt] += __shfl_xor(spout[rt], 16);
                spout[rt] += __shfl_xor(spout[rt], 32);
            }
            if (lq == 0) {
#pragma unroll
                for (int rt = 0; rt < 4; ++rt) {
                    sbuf[(w - 2) * 128 + rt * 16 + lr]      = spin[rt];
                    sbuf[(w - 2) * 128 + 64 + rt * 16 + lr] = spout[rt];
                }
            }
        }
        __syncthreads();
        if (t < 128) {
            const int i = t & 63;
            const int row = base + i;
            if (row < N_NODES) {
                if (t < 64) s_in[row]  = sbuf[i] + sbuf[128 + i];
                else        s_out[row] = sbuf[64 + i] + sbuf[192 + i];
            }
        }
        __syncthreads();   // sbuf reads done before next tile overwrites ldsX
    }
}

// ---------------- Kernel 2: attention + aggregation ----------------
// 4 nodes per wave (16-lane group per node); full 256B h-row per group per
// gather instruction. out = selfb + agg, pure stores (no RMW).
__global__ __launch_bounds__(256) void gat_attn(
    const uint4* __restrict__ hbU4,      // h bf16: [N][16] uint4
    const uint4* __restrict__ selfbU4,   // act_self+bias bf16: [N][16] uint4
    const float* __restrict__ s_in,
    const float* __restrict__ s_out,
    const int* __restrict__ colidx,
    const float* __restrict__ adj,
    float* __restrict__ out)
{
    const int wid  = threadIdx.x >> 6;
    const int lane = threadIdx.x & 63;
    const int lr   = lane & 15;
    const int node = (blockIdx.x * 4 + wid) * 4 + (lane >> 4);   // 16 nodes/block

    float e = -1e30f;
    int c = 0;
    float av = 0.f;
    if (lr < KNB) {
        c  = colidx[node * KNB + lr];
        av = adj[node * KNB + lr];
        const float ev = s_in[node] + s_out[c];
        e = ev > 0.f ? ev : ALPHA * ev;
    }
    float m = e;
#pragma unroll
    for (int msk = 8; msk >= 1; msk >>= 1) m = fmaxf(m, __shfl_xor(m, msk));
    const float p = (lr < KNB) ? __expf(e - m) : 0.f;
    float ssum = p;
#pragma unroll
    for (int msk = 8; msk >= 1; msk >>= 1) ssum += __shfl_xor(ssum, msk);
    const float att = p / ssum * av;

    const uint4 sb = selfbU4[(size_t)node * 16 + lr];
    float accf[8];
    accf[0] = bf2f(sb.x & 0xffffu); accf[1] = bf2f(sb.x >> 16);
    accf[2] = bf2f(sb.y & 0xffffu); accf[3] = bf2f(sb.y >> 16);
    accf[4] = bf2f(sb.z & 0xffffu); accf[5] = bf2f(sb.z >> 16);
    accf[6] = bf2f(sb.w & 0xffffu); accf[7] = bf2f(sb.w >> 16);

    const int gbase = lane & 48;
#pragma unroll
    for (int j = 0; j < KNB; ++j) {
        const float aj = __shfl(att, gbase + j);
        const int   cj = __shfl(c,   gbase + j);
        const uint4 u = hbU4[(size_t)cj * 16 + lr];
        accf[0] = fmaf(aj, bf2f(u.x & 0xffffu), accf[0]);
        accf[1] = fmaf(aj, bf2f(u.x >> 16),     accf[1]);
        accf[2] = fmaf(aj, bf2f(u.y & 0xffffu), accf[2]);
        accf[3] = fmaf(aj, bf2f(u.y >> 16),     accf[3]);
        accf[4] = fmaf(aj, bf2f(u.z & 0xffffu), accf[4]);
        accf[5] = fmaf(aj, bf2f(u.z >> 16),     accf[5]);
        accf[6] = fmaf(aj, bf2f(u.w & 0xffffu), accf[6]);
        accf[7] = fmaf(aj, bf2f(u.w >> 16),     accf[7]);
    }
    float4* op = reinterpret_cast<float4*>(out + (size_t)node * F + lr * 8);
    op[0] = float4{accf[0], accf[1], accf[2], accf[3]};
    op[1] = float4{accf[4], accf[5], accf[6], accf[7]};
}

extern "C" void kernel_launch(void* const* d_in, const int* in_sizes, int n_in,
                              void* d_out, int out_size, void* d_ws, size_t ws_size,
                              hipStream_t stream) {
    const float* x     = (const float*)d_in[0];
    const float* adj   = (const float*)d_in[1];
    // d_in[2] = row: implicit (edges sorted, exactly K per node)
    const int*   col   = (const int*)d_in[3];
    const float* Wself = (const float*)d_in[4];
    const float* Wnb   = (const float*)d_in[5];
    const float* a     = (const float*)d_in[6];
    const float* bias  = (const float*)d_in[7];
    float* out = (float*)d_out;

    char* ws = (char*)d_ws;
    unsigned short* hb    = (unsigned short*)ws;         // 12,800,000 B
    unsigned short* selfb = (unsigned short*)(ws + 12800000);  // 12,800,000 B
    float* s_in  = (float*)(ws + 25600000);              // 200,000 B
    float* s_out = (float*)(ws + 25800000);              // 200,000 B
    unsigned* Wt = (unsigned*)(ws + 26000000);           // 65,536 B

    gat_prep<<<64, 256, 0, stream>>>(Wself, Wnb, Wt);
    const int ntiles = (N_NODES + BM - 1) / BM;                       // 782
    const int nblk   = (ntiles + TILES_PER_BLK - 1) / TILES_PER_BLK;  // 391
    gat_gemm<<<nblk, 256, 0, stream>>>(x, Wt, a, bias, selfb, hb, s_in, s_out);
    gat_attn<<<(N_NODES + 15) / 16, 256, 0, stream>>>((const uint4*)hb, (const uint4*)selfb,
                                                      s_in, s_out, col, adj, out);
}

// Round 9
// 50.615 us; speedup vs baseline: 1.7673x; 1.0390x over previous
//
#include <hip/hip_runtime.h>

constexpr int N_NODES = 50000;
constexpr int KNB = 12;       // neighbors per node
constexpr int F = 128;        // F_IN == F_OUT
constexpr float ALPHA = 0.2f; // LeakyReLU slope
constexpr int BM = 64;        // nodes per GEMM tile
constexpr int TILES_PER_BLK = 2;

typedef __bf16 bf16x8 __attribute__((ext_vector_type(8)));
typedef __bf16 bf16x2 __attribute__((ext_vector_type(2)));
typedef float  f32x4  __attribute__((ext_vector_type(4)));

// Native f32->bf16 pack: compiler emits v_cvt_pk_bf16_f32 (hardware RNE).
__device__ __forceinline__ unsigned pack2(float lo, float hi) {
    bf16x2 v;
    v[0] = (__bf16)lo;
    v[1] = (__bf16)hi;
    return __builtin_bit_cast(unsigned, v);
}
__device__ __forceinline__ float bf2f(unsigned bits16) {
    return __uint_as_float(bits16 << 16);
}

// ---------------- Kernel 0: W transpose + bf16, PRE-SWIZZLED ----------------
// frag(n, k16) = 8 bf16 of W[k16*8 .. k16*8+7][n], n in [0,256)
// stored at uint4 index n*16 + (k16 ^ (n&7))  (the LDS layout the GEMM reads).
__global__ __launch_bounds__(256) void gat_prep(const float* __restrict__ Wself,
                                                const float* __restrict__ Wnb,
                                                unsigned* __restrict__ Wt) {
    const int gid = blockIdx.x * 256 + threadIdx.x;  // 16384 total
    const int n  = gid >> 6;
    const int kp = gid & 63;        // k-pair 0..63
    const int k16 = kp >> 2;
    const int sub = kp & 3;
    const float* src = (n < F) ? (Wself + n) : (Wnb + (n - F));
    const float f0 = src[(size_t)(kp * 2)     * F];
    const float f1 = src[(size_t)(kp * 2 + 1) * F];
    Wt[n * 64 + (k16 ^ (n & 7)) * 4 + sub] = pack2(f0, f1);
}

// ---------------- Kernel 1: fused dual GEMM via MFMA ----------------
// 512 threads = 8 waves; tile 64 rows x 256 cols; wave w owns 32 cols.
//   waves 0..3 (cols 0..127):   selfb = bf16(x@Wself + bias)
//   waves 4..7 (cols 128..255): hb = bf16(x@Wnb); s_in/s_out reduced+stored
// LDS 80KB (W 64 + X 16) -> 2 blocks/CU = 16 waves/CU = 4 waves/SIMD.
__global__ __launch_bounds__(512, 4) void gat_gemm(
    const float* __restrict__ x,
    const unsigned* __restrict__ Wt,   // [256][16] uint4, pre-swizzled
    const float* __restrict__ a,
    const float* __restrict__ bias,
    unsigned short* __restrict__ selfb,
    unsigned short* __restrict__ hb,
    float* __restrict__ s_in,
    float* __restrict__ s_out)
{
    __shared__ uint4 ldsX[BM * 16];    // 16KB
    __shared__ uint4 ldsW[256 * 16];   // 64KB

    const int t = threadIdx.x;
    const int w    = t >> 6;     // 0..7
    const int lane = t & 63;
    const int lq   = lane >> 4;
    const int lr   = lane & 15;

    // ---- stage W via async DMA, once per block (8 chunks of 1KB per wave) ----
    const uint4* Wt4 = reinterpret_cast<const uint4*>(Wt);
#pragma unroll
    for (int i = 0; i < 8; ++i) {
        const int ch = w * 8 + i;
        const uint4* gp = Wt4 + ch * 64 + lane;
        uint4* lp = ldsW + ch * 64;
        __builtin_amdgcn_global_load_lds(
            (const __attribute__((address_space(1))) void*)gp,
            (__attribute__((address_space(3))) void*)lp, 16, 0, 0);
    }

    const bf16x8* fx = reinterpret_cast<const bf16x8*>(ldsX);
    const bf16x8* fw = reinterpret_cast<const bf16x8*>(ldsW);
    float* sbuf = reinterpret_cast<float*>(ldsX);   // 512 floats reused post-MFMA

    for (int it = 0; it < TILES_PER_BLK; ++it) {
        const int base = (blockIdx.x * TILES_PER_BLK + it) * BM;

        // ---- stage X tile (fp32 -> bf16 pack), 2 uint4/thread ----
#pragma unroll
        for (int i = 0; i < 2; ++i) {
            const int idx = t + i * 512;       // row*16 + k16, 0..1023
            const int row = idx >> 4;
            const int k16 = idx & 15;
            int gr = base + row; if (gr >= N_NODES) gr = N_NODES - 1;
            const float4* xp = reinterpret_cast<const float4*>(x + (size_t)gr * F + k16 * 8);
            const float4 f0 = xp[0];
            const float4 f1 = xp[1];
            uint4 v;
            v.x = pack2(f0.x, f0.y); v.y = pack2(f0.z, f0.w);
            v.z = pack2(f1.x, f1.y); v.w = pack2(f1.z, f1.w);
            ldsX[row * 16 + (k16 ^ (row & 7))] = v;
        }
        __syncthreads();   // X visible; first iter also drains W DMA

        f32x4 acc[2][4];   // [col-tile mt][row-tile rt]
#pragma unroll
        for (int mt = 0; mt < 2; ++mt)
#pragma unroll
            for (int rt = 0; rt < 4; ++rt)
                acc[mt][rt] = f32x4{0.f, 0.f, 0.f, 0.f};

#pragma unroll
        for (int s = 0; s < 4; ++s) {
            bf16x8 wf[2], xf[4];
#pragma unroll
            for (int mt = 0; mt < 2; ++mt) {
                const int n = w * 32 + mt * 16 + lr;
                wf[mt] = fw[n * 16 + ((s * 4 + lq) ^ (n & 7))];
            }
#pragma unroll
            for (int rt = 0; rt < 4; ++rt) {
                const int r = rt * 16 + lr;
                xf[rt] = fx[r * 16 + ((s * 4 + lq) ^ (r & 7))];
            }
#pragma unroll
            for (int mt = 0; mt < 2; ++mt)
#pragma unroll
                for (int rt = 0; rt < 4; ++rt)
                    acc[mt][rt] = __builtin_amdgcn_mfma_f32_16x16x32_bf16(wf[mt], xf[rt], acc[mt][rt], 0, 0, 0);
        }

        __syncthreads();   // frag reads done; ldsX reusable as sbuf

        // D mapping: acc[mt][rt][r] -> col = w*32+mt*16+lq*4+r, row = base+rt*16+lr.
        if (w < 4) {
#pragma unroll
            for (int mt = 0; mt < 2; ++mt) {
                const int col0 = w * 32 + mt * 16 + lq * 4;
                const float4 b4 = *reinterpret_cast<const float4*>(bias + col0);
#pragma unroll
                for (int rt = 0; rt < 4; ++rt) {
                    const int row = base + rt * 16 + lr;
                    if (row < N_NODES) {
                        const f32x4 v = acc[mt][rt];
                        uint2 pk{pack2(v[0] + b4.x, v[1] + b4.y), pack2(v[2] + b4.z, v[3] + b4.w)};
                        *reinterpret_cast<uint2*>(selfb + (size_t)row * F + col0) = pk;
                    }
                }
            }
        } else {
            float spin[4] = {0.f, 0.f, 0.f, 0.f};
            float spout[4] = {0.f, 0.f, 0.f, 0.f};
#pragma unroll
            for (int mt = 0; mt < 2; ++mt) {
                const int colh0 = (w - 4) * 32 + mt * 16 + lq * 4;
                const float4 al = *reinterpret_cast<const float4*>(a + colh0);
                const float4 ah = *reinterpret_cast<const float4*>(a + F + colh0);
#pragma unroll
                for (int rt = 0; rt < 4; ++rt) {
                    const int row = base + rt * 16 + lr;
                    const f32x4 v = acc[mt][rt];
                    if (row < N_NODES) {
                        uint2 pk{pack2(v[0], v[1]), pack2(v[2], v[3])};
                        *reinterpret_cast<uint2*>(hb + (size_t)row * F + colh0) = pk;
                    }
                    spin[rt]  = fmaf(v[0], al.x, fmaf(v[1], al.y, fmaf(v[2], al.z, fmaf(v[3], al.w, spin[rt]))));
                    spout[rt] = fmaf(v[0], ah.x, fmaf(v[1], ah.y, fmaf(v[2], ah.z, fmaf(v[3], ah.w, spout[rt]))));
                }
            }
#pragma unroll
            for (int rt = 0; rt < 4; ++rt) {
                spin[rt]  += __shfl_xor(spin[rt], 16);
                spin[rt]  += __shfl_xor(spin[rt], 32);
                spout[rt] += __shfl_xor(spout[rt], 16);
                spout[rt] += __shfl_xor(spout[rt], 32);
            }
            if (lq == 0) {   // lanes 0..15 hold totals for this wave's 32 cols
#pragma unroll
                for (int rt = 0; rt < 4; ++rt) {
                    sbuf[(w - 4) * 128 + rt * 16 + lr]      = spin[rt];
                    sbuf[(w - 4) * 128 + 64 + rt * 16 + lr] = spout[rt];
                }
            }
        }
        __syncthreads();
        if (t < 128) {
            const int i = t & 63;
            const int row = base + i;
            if (row < N_NODES) {
                if (t < 64) s_in[row]  = sbuf[i]      + sbuf[128 + i] + sbuf[256 + i] + sbuf[384 + i];
                else        s_out[row] = sbuf[64 + i] + sbuf[192 + i] + sbuf[320 + i] + sbuf[448 + i];
            }
        }
        __syncthreads();   // sbuf reads done before next tile overwrites ldsX
    }
}

// ---------------- Kernel 2: attention + aggregation ----------------
// 4 nodes per wave (16-lane group per node); full 256B h-row per group per
// gather instruction. out = selfb + agg, pure stores (no RMW).
__global__ __launch_bounds__(256) void gat_attn(
    const uint4* __restrict__ hbU4,      // h bf16: [N][16] uint4
    const uint4* __restrict__ selfbU4,   // act_self+bias bf16: [N][16] uint4
    const float* __restrict__ s_in,
    const float* __restrict__ s_out,
    const int* __restrict__ colidx,
    const float* __restrict__ adj,
    float* __restrict__ out)
{
    const int wid  = threadIdx.x >> 6;
    const int lane = threadIdx.x & 63;
    const int lr   = lane & 15;
    const int node = (blockIdx.x * 4 + wid) * 4 + (lane >> 4);   // 16 nodes/block

    float e = -1e30f;
    int c = 0;
    float av = 0.f;
    if (lr < KNB) {
        c  = colidx[node * KNB + lr];
        av = adj[node * KNB + lr];
        const float ev = s_in[node] + s_out[c];
        e = ev > 0.f ? ev : ALPHA * ev;
    }
    float m = e;
#pragma unroll
    for (int msk = 8; msk >= 1; msk >>= 1) m = fmaxf(m, __shfl_xor(m, msk));
    const float p = (lr < KNB) ? __expf(e - m) : 0.f;
    float ssum = p;
#pragma unroll
    for (int msk = 8; msk >= 1; msk >>= 1) ssum += __shfl_xor(ssum, msk);
    const float att = p / ssum * av;

    const uint4 sb = selfbU4[(size_t)node * 16 + lr];
    float accf[8];
    accf[0] = bf2f(sb.x & 0xffffu); accf[1] = bf2f(sb.x >> 16);
    accf[2] = bf2f(sb.y & 0xffffu); accf[3] = bf2f(sb.y >> 16);
    accf[4] = bf2f(sb.z & 0xffffu); accf[5] = bf2f(sb.z >> 16);
    accf[6] = bf2f(sb.w & 0xffffu); accf[7] = bf2f(sb.w >> 16);

    const int gbase = lane & 48;
#pragma unroll
    for (int j = 0; j < KNB; ++j) {
        const float aj = __shfl(att, gbase + j);
        const int   cj = __shfl(c,   gbase + j);
        const uint4 u = hbU4[(size_t)cj * 16 + lr];
        accf[0] = fmaf(aj, bf2f(u.x & 0xffffu), accf[0]);
        accf[1] = fmaf(aj, bf2f(u.x >> 16),     accf[1]);
        accf[2] = fmaf(aj, bf2f(u.y & 0xffffu), accf[2]);
        accf[3] = fmaf(aj, bf2f(u.y >> 16),     accf[3]);
        accf[4] = fmaf(aj, bf2f(u.z & 0xffffu), accf[4]);
        accf[5] = fmaf(aj, bf2f(u.z >> 16),     accf[5]);
        accf[6] = fmaf(aj, bf2f(u.w & 0xffffu), accf[6]);
        accf[7] = fmaf(aj, bf2f(u.w >> 16),     accf[7]);
    }
    float4* op = reinterpret_cast<float4*>(out + (size_t)node * F + lr * 8);
    op[0] = float4{accf[0], accf[1], accf[2], accf[3]};
    op[1] = float4{accf[4], accf[5], accf[6], accf[7]};
}

extern "C" void kernel_launch(void* const* d_in, const int* in_sizes, int n_in,
                              void* d_out, int out_size, void* d_ws, size_t ws_size,
                              hipStream_t stream) {
    const float* x     = (const float*)d_in[0];
    const float* adj   = (const float*)d_in[1];
    // d_in[2] = row: implicit (edges sorted, exactly K per node)
    const int*   col   = (const int*)d_in[3];
    const float* Wself = (const float*)d_in[4];
    const float* Wnb   = (const float*)d_in[5];
    const float* a     = (const float*)d_in[6];
    const float* bias  = (const float*)d_in[7];
    float* out = (float*)d_out;

    char* ws = (char*)d_ws;
    unsigned short* hb    = (unsigned short*)ws;         // 12,800,000 B
    unsigned short* selfb = (unsigned short*)(ws + 12800000);  // 12,800,000 B
    float* s_in  = (float*)(ws + 25600000);              // 200,000 B
    float* s_out = (float*)(ws + 25800000);              // 200,000 B
    unsigned* Wt = (unsigned*)(ws + 26000000);           // 65,536 B

    gat_prep<<<64, 256, 0, stream>>>(Wself, Wnb, Wt);
    const int ntiles = (N_NODES + BM - 1) / BM;                       // 782
    const int nblk   = (ntiles + TILES_PER_BLK - 1) / TILES_PER_BLK;  // 391
    gat_gemm<<<nblk, 512, 0, stream>>>(x, Wt, a, bias, selfb, hb, s_in, s_out);
    gat_attn<<<(N_NODES + 15) / 16, 256, 0, stream>>>((const uint4*)hb, (const uint4*)selfb,
                                                      s_in, s_out, col, adj, out);
}